// Round 12
// baseline (402.070 us; speedup 1.0000x reference)
//
#include <hip/hip_runtime.h>
#include <cstdint>
#include <cstddef>
#include <cmath>

typedef unsigned short u16;
typedef short v8s __attribute__((ext_vector_type(8)));
typedef float v4f __attribute__((ext_vector_type(4)));

constexpr int SEQ = 4096;
constexpr int FEAT = 2048;
constexpr int F3 = 6144;

// ---------- helpers ----------

__device__ __forceinline__ u16 f2bf(float f) {
  union { float f; uint32_t u; } v; v.f = f;
  uint32_t r = v.u + 0x7FFFu + ((v.u >> 16) & 1u);  // round-to-nearest-even
  return (u16)(r >> 16);
}

__device__ __forceinline__ float bf2f(u16 s) {
  union { uint32_t u; float f; } v; v.u = ((uint32_t)s) << 16;
  return v.f;
}

// async global->LDS, 16B per lane; lds dest is wave-uniform base (HW: base+lane*16)
__device__ __forceinline__ void gld_lds16(const u16* g, u16* l) {
  __builtin_amdgcn_global_load_lds(
      (const __attribute__((address_space(1))) void*)g,
      (__attribute__((address_space(3))) void*)l, 16, 0, 0);
}

// ---------- conversion / transpose ----------

__global__ void cvt_f32_bf16(const float* __restrict__ in, u16* __restrict__ out, int n8) {
  int i = blockIdx.x * 256 + threadIdx.x;
  if (i >= n8) return;
  const float4* p = (const float4*)in + (size_t)i * 2;
  float4 a = p[0], b = p[1];
  union { u16 s[8]; uint4 v; } u;
  u.s[0] = f2bf(a.x); u.s[1] = f2bf(a.y); u.s[2] = f2bf(a.z); u.s[3] = f2bf(a.w);
  u.s[4] = f2bf(b.x); u.s[5] = f2bf(b.y); u.s[6] = f2bf(b.z); u.s[7] = f2bf(b.w);
  *(uint4*)(out + (size_t)i * 8) = u.v;
}

__global__ void transp_f2b(const float* __restrict__ in, int ldin,
                           u16* __restrict__ out, int ldout) {
  __shared__ float tile[32][33];
  int c0 = blockIdx.x * 32, r0 = blockIdx.y * 32;
  int tx = threadIdx.x, ty = threadIdx.y;
#pragma unroll
  for (int p = 0; p < 4; ++p)
    tile[ty + 8 * p][tx] = in[(size_t)(r0 + ty + 8 * p) * ldin + c0 + tx];
  __syncthreads();
#pragma unroll
  for (int p = 0; p < 4; ++p)
    out[(size_t)(c0 + ty + 8 * p) * ldout + r0 + tx] = f2bf(tile[tx][ty + 8 * p]);
}

__global__ void transp_b2b(const u16* __restrict__ in, int ldin,
                           u16* __restrict__ out, int ldout) {
  __shared__ u16 tile[32][33];
  int c0 = blockIdx.x * 32, r0 = blockIdx.y * 32;
  int tx = threadIdx.x, ty = threadIdx.y;
#pragma unroll
  for (int p = 0; p < 4; ++p)
    tile[ty + 8 * p][tx] = in[(size_t)(r0 + ty + 8 * p) * ldin + c0 + tx];
  __syncthreads();
#pragma unroll
  for (int p = 0; p < 4; ++p)
    out[(size_t)(c0 + ty + 8 * p) * ldout + r0 + tx] = tile[tx][ty + 8 * p];
}

// ---------- shared GEMM-phase macros (gemmw + attv) ----------
// r4-proven phase structure (~113us GEMM1, ~910 TF; 0.59 us/block-phase at
// 2 blocks/CU). Tile 128(M)x256(N), BK=32, 256 thr = 4 waves, wave owns
// 128x64. LDS [buf][A 128x32 | B 256x32] = 24 KiB x 3 bufs = 72 KiB.
// Phase: STAGE(t+2) | LOADA(t) | 32 MFMA (B preloaded) | vmcnt(6) | s_barrier
//        | LOADB(t+1)->regs.
// Race-safety (verified r3/r4): vmcnt(6) pre-barrier leaves only this phase's
// 6 stages in flight => post-barrier tile t+1 is in LDS for all waves;
// STAGE(t+2) overwrites tile t-1's buffer whose reads drained pre-BAR(t-1).
// LDS swizzle (proven, conflicts=0): row of 32 elems = 4 chunks of 16B;
// logical chunk c at physical (c + (row>>1))&3; global source pre-rotated.

#define BARW() asm volatile("s_barrier" ::: "memory")
#define VMC6() asm volatile("s_waitcnt vmcnt(6)" ::: "memory")
#define LGKM0() asm volatile("s_waitcnt lgkmcnt(0)" ::: "memory")

#define STAGE(SB, KO) do { \
  u16* Lb = &LDSU[SB][0] + w * 512; \
  gld_lds16(pA0 + (KO), Lb); \
  gld_lds16(pA0 + (size_t)64 * LDA_ + (KO), Lb + 2048); \
  gld_lds16(pB0 + (KO), Lb + 4096); \
  gld_lds16(pB0 + (size_t)64 * LDB_ + (KO), Lb + 4096 + 2048); \
  gld_lds16(pB0 + (size_t)128 * LDB_ + (KO), Lb + 4096 + 4096); \
  gld_lds16(pB0 + (size_t)192 * LDB_ + (KO), Lb + 4096 + 6144); \
} while (0)

#define LOADA(BUF) do { _Pragma("unroll") \
  for (int mi = 0; mi < 8; ++mi) \
    af[mi] = *(const v8s*)(&LDSU[BUF][0] + (mi * 16 + lm) * 32 + lqs); \
} while (0)

#define LOADB(BUF) do { _Pragma("unroll") \
  for (int ni = 0; ni < 4; ++ni) \
    bf4[ni] = *(const v8s*)(&LDSU[BUF][0] + 4096 + (w * 64 + ni * 16 + lm) * 32 + lqs); \
} while (0)

// ---------- gemmw: C = A*B^T + bias, bf16 out (GEMM1 only; r12: reverted to
// the non-lambda r9 body -- the r11 lambda refactor cost GEMM1 ~4us) ----------
template<int LDA_, int LDB_, int LDC_>
__global__ __launch_bounds__(256, 2) void gemmw(
    const u16* __restrict__ A, const u16* __restrict__ B,
    u16* __restrict__ C, int K,
    const float* __restrict__ bias) {
  // column-major within XCD chunk: same-XCD neighbors share the B panel
  const int gx = gridDim.x, gy = gridDim.y;
  const int bb = blockIdx.y * gx + blockIdx.x;
  const int cpx = (gx * gy) >> 3;            // nwg % 8 == 0
  const int sw = (bb & 7) * cpx + (bb >> 3);
  const int bi = sw % gy, bj = sw / gy;
  const int i0 = bi * 128, j0 = bj * 256;

  __shared__ u16 LDSU[3][12288];   // 72 KiB

  const int t = threadIdx.x;
  const int w = t >> 6, l = t & 63;
  const int lm = l & 15, lq = l >> 4;
  const int lqs = ((lq + (lm >> 1)) & 3) * 8;

  const int rA = w * 16 + (l >> 2);
  const int cA = ((((l & 3) - ((rA >> 1) & 3)) & 3)) * 8;
  const u16* pA0 = A + (size_t)(i0 + rA) * LDA_ + cA;
  const u16* pB0 = B + (size_t)(j0 + rA) * LDB_ + cA;

  v4f acc[8][4];
#pragma unroll
  for (int a = 0; a < 8; ++a)
#pragma unroll
    for (int b2 = 0; b2 < 4; ++b2)
      acc[a][b2] = v4f{0.f, 0.f, 0.f, 0.f};

  v8s af[8], bf4[4];

  STAGE(0, 0); STAGE(1, 32);
  VMC6(); BARW();
  LOADB(0);

  const int nt = K >> 5;
  int b0 = 0, b1 = 1;
  for (int tt = 0; tt < nt; tt += 2) {
    const int kc = tt << 5;
    const int s2 = 3 - b0 - b1;
    {
      const int kst = (kc + 64 < K) ? kc + 64 : 0;
      STAGE(s2, kst);
      LOADA(b0);
      __builtin_amdgcn_s_setprio(1);
#pragma unroll
      for (int mi = 0; mi < 8; ++mi)
#pragma unroll
        for (int ni = 0; ni < 4; ++ni)
          acc[mi][ni] = __builtin_amdgcn_mfma_f32_16x16x32_bf16(af[mi], bf4[ni], acc[mi][ni], 0, 0, 0);
      __builtin_amdgcn_s_setprio(0);
      VMC6(); BARW();
      LOADB(b1);
    }
    {
      const int kst = (kc + 96 < K) ? kc + 96 : 0;
      STAGE(b0, kst);
      LOADA(b1);
      __builtin_amdgcn_s_setprio(1);
#pragma unroll
      for (int mi = 0; mi < 8; ++mi)
#pragma unroll
        for (int ni = 0; ni < 4; ++ni)
          acc[mi][ni] = __builtin_amdgcn_mfma_f32_16x16x32_bf16(af[mi], bf4[ni], acc[mi][ni], 0, 0, 0);
      __builtin_amdgcn_s_setprio(0);
      VMC6(); BARW();
      LOADB(s2);
    }
    b1 = b0; b0 = s2;
  }

  // epilogue: C/D layout col=lane&15, row=quad*4+reg [m89-verified]
#pragma unroll
  for (int mi = 0; mi < 8; ++mi) {
#pragma unroll
    for (int ni = 0; ni < 4; ++ni) {
      const int cc = j0 + w * 64 + ni * 16 + lm;
      const float badd = bias[cc];
#pragma unroll
      for (int r = 0; r < 4; ++r) {
        const int rr = i0 + mi * 16 + lq * 4 + r;
        C[(size_t)rr * LDC_ + cc] = f2bf(acc[mi][ni][r] + badd);
      }
    }
  }
}

// ---------- attv: out += att @ v, uniform windows AT 2 BLOCKS/CU ----------
// r12: r9 proved 2/CU co-residency (0.59us/phase) but unpredictable pairing;
// r11 proved perfect balance but solo blocks (1.27us/phase). Combine: pair
// (d=31-p, s=p) has 132 phases of concatenated K-space (4224 K: row d then
// row s); cut into 4 windows [0,1024),[1024,2048),[2048,3072),[3072,4224) ->
// 32/32/32/36 phases. All boundaries and Kd=(d+1)*128 are multiples of 128
// => every segment nt is a multiple of 4 (even, >=4: loop-safe). 16 pairs x
// 8 bj x 4 windows = 512 blocks, ALL ~32 phases -> any co-location balances
// at 64-68 phases/CU AND runs at the co-resident rate. Accumulation: fp32
// atomicAdd into out (proven r7: passed, absmax 0.0158); out memset at start.
template<int LDA_, int LDB_, int LDC_>
__global__ __launch_bounds__(256, 2) void attv(
    const u16* __restrict__ A, const u16* __restrict__ B,
    float* __restrict__ out) {
  const int f = blockIdx.x;        // 512 blocks
  const int p = f & 15;
  const int bj = (f >> 4) & 7;
  const int wi = f >> 7;           // window 0..3
  const int d = 31 - p;
  const int Kd = (d + 1) * 128;    // 2176..4096
  const int ws = wi * 1024;
  const int we = (wi == 3) ? 4224 : ws + 1024;

  int sI0[2], sKs[2], sKe[2];
  int nseg = 0;
  if (ws < Kd) {                   // segment in row-block d
    sI0[nseg] = d * 128; sKs[nseg] = ws; sKe[nseg] = (we < Kd) ? we : Kd; ++nseg;
  }
  if (we > Kd) {                   // segment in row-block s (pair-pos - Kd)
    sI0[nseg] = p * 128; sKs[nseg] = (ws > Kd) ? ws - Kd : 0; sKe[nseg] = we - Kd; ++nseg;
  }
  const int j0 = bj * 256;

  __shared__ u16 LDSU[3][12288];   // 72 KiB

  const int t = threadIdx.x;
  const int w = t >> 6, l = t & 63;
  const int lm = l & 15, lq = l >> 4;
  const int lqs = ((lq + (lm >> 1)) & 3) * 8;

  const int rA = w * 16 + (l >> 2);
  const int cA = ((((l & 3) - ((rA >> 1) & 3)) & 3)) * 8;
  const u16* pB0 = B + (size_t)(j0 + rA) * LDB_ + cA;   // fixed across segments

  auto run_seg = [&](int i0, int ks, int ke) {
    const u16* pA0 = A + (size_t)(i0 + rA) * LDA_ + cA;

    v4f acc[8][4];
#pragma unroll
    for (int a = 0; a < 8; ++a)
#pragma unroll
      for (int b2 = 0; b2 < 4; ++b2)
        acc[a][b2] = v4f{0.f, 0.f, 0.f, 0.f};

    v8s af[8], bf4[4];

    // prologue (vmcnt across segment boundary safe: FIFO retirement ->
    // vmcnt(6) leaves only the newest 6 of THIS segment's 12 stages, so
    // buf0 is fully landed; verified passing in r11's 2-segment blocks)
    STAGE(0, ks); STAGE(1, ks + 32);
    VMC6(); BARW();
    LOADB(0);

    const int nt = (ke - ks) >> 5;      // multiple of 4, >= 4
    int b0 = 0, b1 = 1;
    for (int tt = 0; tt < nt; tt += 2) {
      const int kc = ks + (tt << 5);
      const int s2 = 3 - b0 - b1;
      {
        const int kst = (kc + 64 < ke) ? kc + 64 : ks;
        STAGE(s2, kst);
        LOADA(b0);
        __builtin_amdgcn_s_setprio(1);
#pragma unroll
        for (int mi = 0; mi < 8; ++mi)
#pragma unroll
          for (int ni = 0; ni < 4; ++ni)
            acc[mi][ni] = __builtin_amdgcn_mfma_f32_16x16x32_bf16(af[mi], bf4[ni], acc[mi][ni], 0, 0, 0);
        __builtin_amdgcn_s_setprio(0);
        VMC6(); BARW();
        LOADB(b1);
      }
      {
        const int kst = (kc + 96 < ke) ? kc + 96 : ks;
        STAGE(b0, kst);
        LOADA(b1);
        __builtin_amdgcn_s_setprio(1);
#pragma unroll
        for (int mi = 0; mi < 8; ++mi)
#pragma unroll
          for (int ni = 0; ni < 4; ++ni)
            acc[mi][ni] = __builtin_amdgcn_mfma_f32_16x16x32_bf16(af[mi], bf4[ni], acc[mi][ni], 0, 0, 0);
        __builtin_amdgcn_s_setprio(0);
        VMC6(); BARW();
        LOADB(s2);
      }
      b1 = b0; b0 = s2;
    }

    // epilogue: fp32 atomic accumulate into out
#pragma unroll
    for (int mi = 0; mi < 8; ++mi) {
#pragma unroll
      for (int ni = 0; ni < 4; ++ni) {
        const int cc = j0 + w * 64 + ni * 16 + lm;
#pragma unroll
        for (int r = 0; r < 4; ++r) {
          const int rr = i0 + mi * 16 + lq * 4 + r;
          atomicAdd(out + (size_t)rr * LDC_ + cc, acc[mi][ni][r]);
        }
      }
    }
  };

  run_seg(sI0[0], sKs[0], sKe[0]);
  if (nseg == 2) run_seg(sI0[1], sKs[1], sKe[1]);
}

#undef STAGE
#undef LOADA
#undef LOADB

// ---------- gemm8tri: 256x256 8-phase GEMM on a flat triangular grid ----------
// r1/r7-verified schedule; GEMM2's 136-block grid (0.53/CU -> makespan = one
// block-time). bf16, 512 thr = 8 waves (2Mx4N), wave owns 128x64, BK=64,
// double-buffered LDS 128 KiB, K % 128 == 0. Counted vmcnt(6) at P4/P8 only.
// LDS swizzle: chunk rotation (c + row) & 7, global source pre-rotated.

#define LDA8(BUF, MH) do { _Pragma("unroll") \
  for (int fi = 0; fi < 4; ++fi) { \
    const u16* ap = &As8[BUF][wr][(MH) * 4096 + fi * 1024]; \
    af[fi][0] = *(const v8s*)(ap + off0); \
    af[fi][1] = *(const v8s*)(ap + off1); \
  } } while (0)

#define LDB8(BUF) do { _Pragma("unroll") \
  for (int ni = 0; ni < 4; ++ni) { \
    const u16* bp = &Bs8[BUF][bh][bo + ni * 1024]; \
    bfr[ni][0] = *(const v8s*)(bp + off0); \
    bfr[ni][1] = *(const v8s*)(bp + off1); \
  } } while (0)

#define MMA8(MH, NL) do { _Pragma("unroll") \
  for (int fi = 0; fi < 4; ++fi) { _Pragma("unroll") \
    for (int nn = 0; nn < 2; ++nn) { \
      acc[(MH)*4+fi][(NL)+nn] = __builtin_amdgcn_mfma_f32_16x16x32_bf16( \
          af[fi][0], bfr[(NL)+nn][0], acc[(MH)*4+fi][(NL)+nn], 0, 0, 0); \
      acc[(MH)*4+fi][(NL)+nn] = __builtin_amdgcn_mfma_f32_16x16x32_bf16( \
          af[fi][1], bfr[(NL)+nn][1], acc[(MH)*4+fi][(NL)+nn], 0, 0, 0); \
    } } } while (0)

#define STG8A(BUF, H, KO) do { \
  gld_lds16(Ag + (size_t)(H) * 128 * LDA_ + (KO), &As8[BUF][H][w8 * 1024]); \
  gld_lds16(Ag + ((size_t)(H) * 128 + 8) * LDA_ + (KO), &As8[BUF][H][w8 * 1024 + 512]); \
  } while (0)

#define STG8B(BUF, H, KO) do { \
  gld_lds16(Bg + (size_t)(H) * 128 * LDB_ + (KO), &Bs8[BUF][H][w8 * 1024]); \
  gld_lds16(Bg + ((size_t)(H) * 128 + 8) * LDB_ + (KO), &Bs8[BUF][H][w8 * 1024 + 512]); \
  } while (0)

template<int LDA_, int LDB_, int LDC_>
__global__ __launch_bounds__(512, 2) void gemm8tri(
    const u16* __restrict__ A, const u16* __restrict__ B,
    u16* __restrict__ C, int K, float scale) {
  // flat lower-triangular grid (bj <= bi), XCD-chunked; gridDim.x % 8 == 0
  const int b = blockIdx.x;
  const int cpx = (int)gridDim.x >> 3;
  const int s = (b & 7) * cpx + (b >> 3);
  int bi = (int)((sqrtf(8.f * s + 1.f) - 1.f) * 0.5f);
  while ((bi + 1) * (bi + 2) / 2 <= s) ++bi;
  while (bi * (bi + 1) / 2 > s) --bi;
  const int bj = s - bi * (bi + 1) / 2;
  const int i0 = bi * 256, j0 = bj * 256;

  __shared__ u16 As8[2][2][8192];  // [buf][half][128*64], 64 KiB
  __shared__ u16 Bs8[2][2][8192];  // 64 KiB

  const int t = threadIdx.x;
  const int w8 = t >> 6, l = t & 63;
  const int wr = w8 >> 2, wc = w8 & 3;
  const int lm = l & 15, lq = l >> 4;
  const int bh = wc >> 1, bo = (wc & 1) * 4096;

  const int off0 = lm * 64 + ((lq + lm) & 7) * 8;        // s=0
  const int off1 = lm * 64 + ((lq + lm + 4) & 7) * 8;    // s=1

  const int srow = w8 * 16 + (l >> 3);
  const int scol = (((l & 7) - (l >> 3)) & 7) * 8;
  const u16* Ag = A + (size_t)(i0 + srow) * LDA_ + scol;
  const u16* Bg = B + (size_t)(j0 + srow) * LDB_ + scol;

  v4f acc[8][4];
#pragma unroll
  for (int a = 0; a < 8; ++a)
#pragma unroll
    for (int b2 = 0; b2 < 4; ++b2)
      acc[a][b2] = v4f{0.f, 0.f, 0.f, 0.f};

  v8s af[4][2], bfr[4][2];

  STG8B(0, 0, 0); STG8B(0, 1, 0); STG8A(0, 0, 0); STG8A(0, 1, 0);
  STG8B(1, 0, 64); STG8B(1, 1, 64); STG8A(1, 0, 64);
  VMC6(); BARW();

  const int nit = K >> 7;  // K % 128 == 0
  for (int it = 0; it < nit; ++it) {
    const int kc = it << 7;
    const int k1 = kc + 64;
    int k2 = kc + 128; if (k2 >= K) k2 = 0;
    int k3 = kc + 192; if (k3 >= K) k3 = 0;

    LDA8(0, 0); LDB8(0);
    STG8A(1, 1, k1);
    BARW(); LGKM0();
    __builtin_amdgcn_s_setprio(1); MMA8(0, 0); __builtin_amdgcn_s_setprio(0);
    BARW();
    STG8B(0, 0, k2);
    BARW();
    __builtin_amdgcn_s_setprio(1); MMA8(0, 2); __builtin_amdgcn_s_setprio(0);
    BARW();
    LDA8(0, 1);
    STG8B(0, 1, k2);
    BARW(); LGKM0();
    __builtin_amdgcn_s_setprio(1); MMA8(1, 0); __builtin_amdgcn_s_setprio(0);
    BARW();
    STG8A(0, 0, k2);
    BARW();
    __builtin_amdgcn_s_setprio(1); MMA8(1, 2); __builtin_amdgcn_s_setprio(0);
    VMC6(); BARW();
    LDA8(1, 0); LDB8(1);
    STG8A(0, 1, k2);
    BARW(); LGKM0();
    __builtin_amdgcn_s_setprio(1); MMA8(0, 0); __builtin_amdgcn_s_setprio(0);
    BARW();
    STG8B(1, 0, k3);
    BARW();
    __builtin_amdgcn_s_setprio(1); MMA8(0, 2); __builtin_amdgcn_s_setprio(0);
    BARW();
    LDA8(1, 1);
    STG8B(1, 1, k3);
    BARW(); LGKM0();
    __builtin_amdgcn_s_setprio(1); MMA8(1, 0); __builtin_amdgcn_s_setprio(0);
    BARW();
    STG8A(1, 0, k3);
    BARW();
    __builtin_amdgcn_s_setprio(1); MMA8(1, 2); __builtin_amdgcn_s_setprio(0);
    VMC6(); BARW();
  }

  // epilogue: C/D layout col=lane&15, row=quad*4+reg [m89-verified]
#pragma unroll
  for (int mi = 0; mi < 8; ++mi) {
#pragma unroll
    for (int ni = 0; ni < 4; ++ni) {
      const int cc = j0 + wc * 64 + ni * 16 + lm;
#pragma unroll
      for (int r = 0; r < 4; ++r) {
        const int rr = i0 + wr * 128 + mi * 16 + lq * 4 + r;
        C[(size_t)rr * LDC_ + cc] = f2bf(acc[mi][ni][r] * scale);
      }
    }
  }
}

#undef LDA8
#undef LDB8
#undef MMA8
#undef STG8A
#undef STG8B

// ---------- row softmax with causal + padding mask (single bf16 input) ----------
// 3-pass branch-free, vectorized (r11; passed)
__global__ __launch_bounds__(256) void softmax_rows(
    const u16* __restrict__ S0,
    u16* __restrict__ att, const int* __restrict__ npad_p) {
  const int i = blockIdx.x;
  const int np = *npad_p;
  const int kend = ((i >> 7) + 1) << 7;   // 128-rounded: matches attv read range
  const u16* r0 = S0 + (size_t)i * SEQ;
  u16* arow = att + (size_t)i * SEQ;
  const int t = threadIdx.x;
  const int w = t >> 6, l = t & 63;
  __shared__ float sm[4], ss[4];

  float m = -3.0e38f;
  for (int j0b = t * 8; j0b < kend; j0b += 2048) {
    union { u16 s8[8]; uint4 v; } ui;
    ui.v = *(const uint4*)(r0 + j0b);
#pragma unroll
    for (int q = 0; q < 8; ++q) {
      const int j = j0b + q;
      const float v = (j >= np && j <= i) ? bf2f(ui.s8[q]) : -3.0e38f;
      m = fmaxf(m, v);
    }
  }
#pragma unroll
  for (int off = 32; off > 0; off >>= 1) m = fmaxf(m, __shfl_xor(m, off));
  if (l == 0) sm[w] = m;
  __syncthreads();
  const float M = fmaxf(fmaxf(sm[0], sm[1]), fmaxf(sm[2], sm[3]));

  float s = 0.f;
  for (int j0b = t * 8; j0b < kend; j0b += 2048) {
    union { u16 s8[8]; uint4 v; } ui;
    ui.v = *(const uint4*)(r0 + j0b);
#pragma unroll
    for (int q = 0; q < 8; ++q) {
      const int j = j0b + q;
      const float v = (j >= np && j <= i) ? bf2f(ui.s8[q]) : -3.0e38f;
      s += __expf(v - M);
    }
  }
#pragma unroll
  for (int off = 32; off > 0; off >>= 1) s += __shfl_xor(s, off);
  if (l == 0) ss[w] = s;
  __syncthreads();
  const float inv = 1.f / (ss[0] + ss[1] + ss[2] + ss[3]);

  for (int j0b = t * 8; j0b < kend; j0b += 2048) {
    union { u16 s8[8]; uint4 v; } ui, uo;
    ui.v = *(const uint4*)(r0 + j0b);
#pragma unroll
    for (int q = 0; q < 8; ++q) {
      const int j = j0b + q;
      float a = 0.f;
      if (j >= np && j <= i)
        a = __expf(bf2f(ui.s8[q]) - M) * inv;
      uo.s8[q] = f2bf(a);
    }
    *(uint4*)(arow + j0b) = uo.v;
  }
}

// ---------- launch ----------

extern "C" void kernel_launch(void* const* d_in, const int* in_sizes, int n_in,
                              void* d_out, int out_size, void* d_ws, size_t ws_size,
                              hipStream_t stream) {
  const float* x = (const float*)d_in[0];
  const float* W = (const float*)d_in[1];
  const float* b = (const float*)d_in[2];
  const int* npad = (const int*)d_in[3];
  float* out = (float*)d_out;

  // workspace (136 MB):
  // [xb 16MB | Wt 24MB] reused as att 32MB ][ qkvb 48MB ][ vt 16MB ][ sc0 32MB ]
  char* p = (char*)d_ws;
  u16* xb = (u16*)p;
  u16* Wt = (u16*)(p + (size_t)SEQ * FEAT * 2);
  u16* att = (u16*)p;
  p += (size_t)SEQ * FEAT * 2 + (size_t)F3 * FEAT * 2;
  u16* qkvb = (u16*)p;  p += (size_t)SEQ * F3 * 2;
  u16* vt   = (u16*)p;  p += (size_t)FEAT * SEQ * 2;
  u16* sc0  = (u16*)p;  p += (size_t)SEQ * SEQ * 2;   // bf16 scores
  if (ws_size < (size_t)(p - (char*)d_ws)) return;

  const float scale = 0.02209708691207961f;  // 1/sqrt(2048)

  // zero d_out (attv atomically accumulates into it)
  hipMemsetAsync(d_out, 0, (size_t)SEQ * FEAT * sizeof(float), stream);

  cvt_f32_bf16<<<SEQ * FEAT / 8 / 256, 256, 0, stream>>>(x, xb, SEQ * FEAT / 8);
  transp_f2b<<<dim3(F3 / 32, FEAT / 32), dim3(32, 8), 0, stream>>>(W, F3, Wt, FEAT);
  // qkv = x @ W + b: 128x256 tiles, grid 24x32 = 768 blocks (2 blocks/CU)
  gemmw<FEAT, FEAT, F3><<<dim3(F3 / 256, SEQ / 128), 256, 0, stream>>>(
      xb, Wt, qkvb, FEAT, b);
  transp_b2b<<<dim3(FEAT / 32, SEQ / 32), dim3(32, 8), 0, stream>>>(
      qkvb + 2 * FEAT, F3, vt, SEQ);
  // scores = (q @ k^T)/sqrt(F): 8-phase 256^2, flat triangular grid, 136 blocks
  gemm8tri<F3, F3, SEQ><<<dim3(136), 512, 0, stream>>>(
      qkvb, qkvb + FEAT, sc0, FEAT, scale);
  softmax_rows<<<SEQ, 256, 0, stream>>>(sc0, att, npad);
  // out += att @ v: 512 uniform ~32-phase windows (2 blocks/CU co-resident,
  // balanced under ANY co-location), fp32 atomicAdd
  attv<SEQ, SEQ, FEAT><<<dim3(512), 256, 0, stream>>>(att, vt, out);
}